// Round 9
// baseline (185.832 us; speedup 1.0000x reference)
//
#include <hip/hip_runtime.h>

#define BB 8192
#define KCNT 50

typedef __attribute__((ext_vector_type(8))) short bf16x8;
typedef __attribute__((ext_vector_type(4))) float f32x4;

__device__ __forceinline__ ushort f2bf(float f) {
    union { float f; unsigned u; } v; v.f = f;
    unsigned r = v.u + 0x7FFFu + ((v.u >> 16) & 1u);
    return (ushort)(r >> 16);
}
__device__ __forceinline__ float bf2f(ushort h) {
    union { unsigned u; float f; } v; v.u = ((unsigned)h) << 16;
    return v.f;
}

// fragment-major index: frag f=(nt*KC+kc) holds a 16n x 32k block as
// 64 lanes x 16B, so reads at f*1024B + lane*16B are perfectly coalesced.
__device__ __forceinline__ int fidx(int K, int n, int k) {
    int nt = n >> 4, ln = n & 15, kc = k >> 5, quad = (k >> 3) & 3, j = k & 7;
    return (((nt * (K >> 5) + kc) * 4 + quad) * 16 + ln) * 8 + j;
}

// ---- prep: all 6 weights [K][N] fp32 -> fragment-major bf16 ----
__global__ __launch_bounds__(256) void prep_weights(
    const float* __restrict__ s0, ushort* __restrict__ d0,   // Wkg 64x64
    const float* __restrict__ s1, ushort* __restrict__ d1,   // W1a 512x128
    const float* __restrict__ s2, ushort* __restrict__ d2,   // W1b 128x512
    const float* __restrict__ s3, ushort* __restrict__ d3,   // W1c 512x128
    const float* __restrict__ s4, ushort* __restrict__ d4,   // W1d 128x64
    const float* __restrict__ s5, ushort* __restrict__ d5)   // W2 64x1024
{
    int gid = blockIdx.x * 256 + threadIdx.x;
    const float* s; ushort* d; int K, N, base;
    if      (gid < 4096)   { s = s0; d = d0; K = 64;  N = 64;   base = 0; }
    else if (gid < 69632)  { s = s1; d = d1; K = 512; N = 128;  base = 4096; }
    else if (gid < 135168) { s = s2; d = d2; K = 128; N = 512;  base = 69632; }
    else if (gid < 200704) { s = s3; d = d3; K = 512; N = 128;  base = 135168; }
    else if (gid < 208896) { s = s4; d = d4; K = 128; N = 64;   base = 200704; }
    else if (gid < 274432) { s = s5; d = d5; K = 64;  N = 1024; base = 208896; }
    else return;
    int e = gid - base;          // e = k*N + n  (coalesced read)
    int k = e / N, n = e % N;
    d[fidx(K, n, k)] = f2bf(s[e]);
}

// ---- per-wave layer: A from LDS (or global fp32), B-frags from global
// frag-major weights (L2-hot, 16B/lane coalesced), C to LDS (or global).
// Computes a 16-row tile; only ROWS rows are real (extras are duplicates).
template<int K, int N, int STRIN, int STROUT, int ROWS, bool AGLOBAL, bool RELU, bool ADDK, bool OUTGLOBAL>
__device__ __forceinline__ void wave_layer(
    const ushort* ldsIn, const float* __restrict__ gA, ushort* ldsOut,
    const ushort* __restrict__ Wf, const float* __restrict__ bias,
    const ushort* knowL, float* __restrict__ gOut,
    int m0, int lane, int w)
{
    constexpr int KC  = K / 32;
    constexpr int NTH = N / 64;       // n-tiles per wave (4 waves)
    const int ln = lane & 15, quad = lane >> 4;

    bf16x8 a[KC];
    if constexpr (AGLOBAL) {
        const int arow = m0 + (ln & (ROWS - 1));   // clamp duplicates into range
        #pragma unroll
        for (int kc = 0; kc < KC; ++kc) {
            const float* p = gA + (size_t)arow * K + kc * 32 + quad * 8;
            float4 u = *(const float4*)p;
            float4 v = *(const float4*)(p + 4);
            bf16x8 r;
            r[0] = (short)f2bf(u.x); r[1] = (short)f2bf(u.y);
            r[2] = (short)f2bf(u.z); r[3] = (short)f2bf(u.w);
            r[4] = (short)f2bf(v.x); r[5] = (short)f2bf(v.y);
            r[6] = (short)f2bf(v.z); r[7] = (short)f2bf(v.w);
            a[kc] = r;
        }
    } else {
        #pragma unroll
        for (int kc = 0; kc < KC; ++kc)
            a[kc] = *(const bf16x8*)&ldsIn[ln * STRIN + kc * 32 + quad * 8];
    }

    f32x4 acc[NTH];
    #pragma unroll
    for (int nt = 0; nt < NTH; ++nt) acc[nt] = (f32x4){0.f, 0.f, 0.f, 0.f};

    #pragma unroll
    for (int kc = 0; kc < KC; ++kc)
        #pragma unroll
        for (int nt = 0; nt < NTH; ++nt) {
            bf16x8 b = *(const bf16x8*)(Wf + ((size_t)((w * NTH + nt) * KC + kc) * 64 + lane) * 8);
            acc[nt] = __builtin_amdgcn_mfma_f32_16x16x32_bf16(a[kc], b, acc[nt], 0, 0, 0);
        }

    #pragma unroll
    for (int nt = 0; nt < NTH; ++nt) {
        const int col = (w * NTH + nt) * 16 + ln;
        const float bv = bias[col];
        #pragma unroll
        for (int i = 0; i < 4; ++i) {
            const int row = quad * 4 + i;
            float v = acc[nt][i] + bv;
            if constexpr (RELU) v = fmaxf(v, 0.f);
            if constexpr (ADDK) v += bf2f(knowL[row * 72 + col]);
            if constexpr (OUTGLOBAL) {
                if (row < ROWS) gOut[(size_t)(m0 + row) * N + col] = v;
            } else {
                ldsOut[row * STROUT + col] = f2bf(v);
            }
        }
    }
}

// ===== megakernel: knowledge + whole MLP. 1024 blocks x 256 threads (4 waves),
// 8 batch rows per block -> 3 blocks/CU = 12 waves/CU (regs ~140 <= 512/3). =====
__global__ __launch_bounds__(256, 3) void mega(
    const float* __restrict__ x, const float* __restrict__ kg,
    const int* __restrict__ idx, const int* __restrict__ mask,
    const ushort* __restrict__ Wkgf, const float* __restrict__ bkg,
    const ushort* __restrict__ W1at, const float* __restrict__ b1a,
    const ushort* __restrict__ W1bt, const float* __restrict__ b1b,
    const ushort* __restrict__ W1ct, const float* __restrict__ b1c,
    const ushort* __restrict__ W1dt, const float* __restrict__ b1d,
    const ushort* __restrict__ W2t,  const float* __restrict__ b2,
    float* __restrict__ out)
{
    __shared__ ushort bufA[16 * 520];   // h2 (rows 8-15 are duplicates)
    __shared__ ushort bufB[16 * 136];   // h1 / h3
    __shared__ ushort bufC[16 * 72];    // relu(h4)+know
    __shared__ ushort knowL[16 * 72];   // knowledge, rows 0-7 real
    __shared__ int    sidxL[4][64];     // per-wave compacted indices

    const int t = threadIdx.x;
    const int w = t >> 6, lane = t & 63, ln = lane & 15, quad = lane >> 4;
    const int m0 = blockIdx.x * 8;

    // ---------- knowledge: wave w handles batches m0 + w*2 .. +1 ----------
    // Wkg B-frags hoisted to registers (8 x 16B/lane, L2-hot)
    bf16x8 wb[4][2];
    #pragma unroll
    for (int nt = 0; nt < 4; ++nt)
        #pragma unroll
        for (int s = 0; s < 2; ++s)
            wb[nt][s] = *(const bf16x8*)(Wkgf + ((size_t)((nt * 2 + s) * 64 + lane)) * 8);

    // preload idx/mask for this wave's 2 sub-batches (coalesced, lanes 0..49)
    int ids[2], mks[2];
    #pragma unroll
    for (int sub = 0; sub < 2; ++sub) {
        const int b = m0 + w * 2 + sub;
        ids[sub] = 0; mks[sub] = 0;
        if (lane < KCNT) {
            ids[sub] = idx[(size_t)b * KCNT + lane];
            mks[sub] = mask[(size_t)b * KCNT + lane];
        }
    }

    #pragma unroll 1
    for (int sub = 0; sub < 2; ++sub) {
        unsigned long long bal = __ballot(mks[sub] != 0);
        const int cnt = __popcll(bal);
        if (mks[sub]) {
            int pos = __popcll(bal & ((1ull << lane) - 1ull));
            sidxL[w][pos] = ids[sub];
        }
        // wave-local LDS RAW: in-wave DS ordering handles visibility.

        // compacted gather direct to A-registers
        bf16x8 a[4][2];
        #pragma unroll
        for (int mt = 0; mt < 4; ++mt) {
            const int r = mt * 16 + ln;
            const bool val = r < cnt;
            #pragma unroll
            for (int s = 0; s < 2; ++s) {
                bf16x8 rr = (bf16x8){0, 0, 0, 0, 0, 0, 0, 0};
                if (val) {
                    const float* p = kg + (size_t)sidxL[w][r] * 64 + s * 32 + quad * 8;
                    float4 u = *(const float4*)p;
                    float4 v = *(const float4*)(p + 4);
                    rr[0] = (short)f2bf(u.x); rr[1] = (short)f2bf(u.y);
                    rr[2] = (short)f2bf(u.z); rr[3] = (short)f2bf(u.w);
                    rr[4] = (short)f2bf(v.x); rr[5] = (short)f2bf(v.y);
                    rr[6] = (short)f2bf(v.z); rr[7] = (short)f2bf(v.w);
                }
                a[mt][s] = rr;
            }
        }

        f32x4 acc[4][4];
        #pragma unroll
        for (int i = 0; i < 4; ++i)
            #pragma unroll
            for (int j = 0; j < 4; ++j)
                acc[i][j] = (f32x4){0.f, 0.f, 0.f, 0.f};

        #pragma unroll
        for (int s = 0; s < 2; ++s)
            #pragma unroll
            for (int nt = 0; nt < 4; ++nt)
                #pragma unroll
                for (int mt = 0; mt < 4; ++mt)
                    acc[mt][nt] = __builtin_amdgcn_mfma_f32_16x16x32_bf16(
                        a[mt][s], wb[nt][s], acc[mt][nt], 0, 0, 0);

        // relu(c + bkg) for rows < cnt, column-sum, wave reduce
        float cs[4] = {0.f, 0.f, 0.f, 0.f};
        #pragma unroll
        for (int mt = 0; mt < 4; ++mt)
            #pragma unroll
            for (int i = 0; i < 4; ++i) {
                const int row = mt * 16 + quad * 4 + i;
                const float mk = (row < cnt) ? 1.f : 0.f;
                #pragma unroll
                for (int nt = 0; nt < 4; ++nt)
                    cs[nt] += mk * fmaxf(acc[mt][nt][i] + bkg[nt * 16 + ln], 0.f);
            }
        #pragma unroll
        for (int nt = 0; nt < 4; ++nt) {
            cs[nt] += __shfl_xor(cs[nt], 16, 64);
            cs[nt] += __shfl_xor(cs[nt], 32, 64);
        }
        if (quad == 0) {
            #pragma unroll
            for (int nt = 0; nt < 4; ++nt)
                knowL[(w * 2 + sub) * 72 + nt * 16 + ln] = f2bf(cs[nt]);
        }
    }

    // ---------- MLP chain (knowL visible to L4 via the L1..L3 barriers) ----------
    // L1: h1 = relu(x @ W1a + b1a)            512 -> 128 (A from global fp32)
    wave_layer<512, 128, 0, 136, 8, true, true, false, false>(
        nullptr, x, bufB, W1at, b1a, nullptr, nullptr, m0, lane, w);
    __syncthreads();
    // L2: h2 = relu(h1 @ W1b + b1b)           128 -> 512
    wave_layer<128, 512, 136, 520, 8, false, true, false, false>(
        bufB, nullptr, bufA, W1bt, b1b, nullptr, nullptr, m0, lane, w);
    __syncthreads();
    // L3: h3 = relu(h2 @ W1c + b1c)           512 -> 128
    wave_layer<512, 128, 520, 136, 8, false, true, false, false>(
        bufA, nullptr, bufB, W1ct, b1c, nullptr, nullptr, m0, lane, w);
    __syncthreads();
    // L4: c = relu(h3 @ W1d + b1d) + knowledge   128 -> 64
    wave_layer<128, 64, 136, 72, 8, false, true, true, false>(
        bufB, nullptr, bufC, W1dt, b1d, knowL, nullptr, m0, lane, w);
    __syncthreads();
    // L5: out = c @ W2 + b2 (fp32 to global, rows 0-7)  64 -> 1024
    wave_layer<64, 1024, 72, 0, 8, false, false, false, true>(
        bufC, nullptr, nullptr, W2t, b2, nullptr, out, m0, lane, w);
}

extern "C" void kernel_launch(void* const* d_in, const int* in_sizes, int n_in,
                              void* d_out, int out_size, void* d_ws, size_t ws_size,
                              hipStream_t stream)
{
    const float* x    = (const float*)d_in[0];
    const float* kg   = (const float*)d_in[1];
    const int*   idx  = (const int*)d_in[2];
    const int*   mask = (const int*)d_in[3];
    const float* Wkg  = (const float*)d_in[4];
    const float* bkg  = (const float*)d_in[5];
    const float* W1a  = (const float*)d_in[6];
    const float* b1a  = (const float*)d_in[7];
    const float* W1b  = (const float*)d_in[8];
    const float* b1b  = (const float*)d_in[9];
    const float* W1c  = (const float*)d_in[10];
    const float* b1c  = (const float*)d_in[11];
    const float* W1d  = (const float*)d_in[12];
    const float* b1d  = (const float*)d_in[13];
    const float* W2   = (const float*)d_in[14];
    const float* b2   = (const float*)d_in[15];
    float* out = (float*)d_out;

    // ws (ushorts): frag-major bf16 weights only (~540 KB)
    ushort* Wkgt = (ushort*)d_ws;                    // 64*64
    ushort* W1at = Wkgt + 64 * 64;                   // 512*128
    ushort* W1bt = W1at + 512 * 128;                 // 128*512
    ushort* W1ct = W1bt + 128 * 512;                 // 512*128
    ushort* W1dt = W1ct + 512 * 128;                 // 128*64
    ushort* W2t  = W1dt + 128 * 64;                  // 64*1024

    prep_weights<<<(274432 + 255) / 256, 256, 0, stream>>>(
        Wkg, Wkgt, W1a, W1at, W1b, W1bt, W1c, W1ct, W1d, W1dt, W2, W2t);

    mega<<<BB / 8, 256, 0, stream>>>(
        x, kg, idx, mask, Wkgt, bkg,
        W1at, b1a, W1bt, b1b, W1ct, b1c, W1dt, b1d, W2t, b2, out);
}

// Round 10
// 159.343 us; speedup vs baseline: 1.1662x; 1.1662x over previous
//
#include <hip/hip_runtime.h>
#include <hip/hip_bf16.h>

#define BB 8192
#define KCNT 50

typedef __attribute__((ext_vector_type(8))) short bf16x8;
typedef __attribute__((ext_vector_type(4))) float f32x4;

__device__ __forceinline__ ushort f2bf(float f) {
    union { float f; unsigned u; } v; v.f = f;
    unsigned r = v.u + 0x7FFFu + ((v.u >> 16) & 1u);
    return (ushort)(r >> 16);
}
__device__ __forceinline__ float bf2f(ushort h) {
    union { unsigned u; float f; } v; v.u = ((unsigned)h) << 16;
    return v.f;
}
// packed f32x8 -> bf16x8 via v_cvt_pk_bf16_f32 (RNE)
__device__ __forceinline__ bf16x8 cvt8(float4 u, float4 v) {
    union { bf16x8 r; __hip_bfloat162 h[4]; } o;
    o.h[0] = __float22bfloat162_rn(float2{u.x, u.y});
    o.h[1] = __float22bfloat162_rn(float2{u.z, u.w});
    o.h[2] = __float22bfloat162_rn(float2{v.x, v.y});
    o.h[3] = __float22bfloat162_rn(float2{v.z, v.w});
    return o.r;
}

// fragment-major index: frag f=(nt*KC+kc) holds a 16n x 32k block as
// 64 lanes x 16B, so reads at f*1024B + lane*16B are perfectly coalesced.
__device__ __forceinline__ int fidx(int K, int n, int k) {
    int nt = n >> 4, ln = n & 15, kc = k >> 5, quad = (k >> 3) & 3, j = k & 7;
    return (((nt * (K >> 5) + kc) * 4 + quad) * 16 + ln) * 8 + j;
}

// ---- prep: all 6 weights [K][N] fp32 -> fragment-major bf16 ----
__global__ __launch_bounds__(256) void prep_weights(
    const float* __restrict__ s0, ushort* __restrict__ d0,   // Wkg 64x64
    const float* __restrict__ s1, ushort* __restrict__ d1,   // W1a 512x128
    const float* __restrict__ s2, ushort* __restrict__ d2,   // W1b 128x512
    const float* __restrict__ s3, ushort* __restrict__ d3,   // W1c 512x128
    const float* __restrict__ s4, ushort* __restrict__ d4,   // W1d 128x64
    const float* __restrict__ s5, ushort* __restrict__ d5)   // W2 64x1024
{
    int gid = blockIdx.x * 256 + threadIdx.x;
    const float* s; ushort* d; int K, N, base;
    if      (gid < 4096)   { s = s0; d = d0; K = 64;  N = 64;   base = 0; }
    else if (gid < 69632)  { s = s1; d = d1; K = 512; N = 128;  base = 4096; }
    else if (gid < 135168) { s = s2; d = d2; K = 128; N = 512;  base = 69632; }
    else if (gid < 200704) { s = s3; d = d3; K = 512; N = 128;  base = 135168; }
    else if (gid < 208896) { s = s4; d = d4; K = 128; N = 64;   base = 200704; }
    else if (gid < 274432) { s = s5; d = d5; K = 64;  N = 1024; base = 208896; }
    else return;
    int e = gid - base;          // e = k*N + n  (coalesced read)
    int k = e / N, n = e % N;
    d[fidx(K, n, k)] = f2bf(s[e]);
}

// ---- per-wave layer (R7 structure): A from LDS (or global fp32), B-frags
// from global frag-major weights (L2-hot, 16B/lane), C to LDS (or global).
template<int K, int N, int STRIN, int STROUT, bool AGLOBAL, bool RELU, bool ADDK, bool OUTGLOBAL>
__device__ __forceinline__ void wave_layer(
    const ushort* ldsIn, const float* __restrict__ gA, ushort* ldsOut,
    const ushort* __restrict__ Wf, const float* __restrict__ bias,
    const ushort* knowL, float* __restrict__ gOut,
    int m0, int lane, int w)
{
    constexpr int KC  = K / 32;
    constexpr int NTH = N / 64;       // n-tiles per wave (4 waves)
    const int ln = lane & 15, quad = lane >> 4;

    bf16x8 a[KC];
    if constexpr (AGLOBAL) {
        #pragma unroll
        for (int kc = 0; kc < KC; ++kc) {
            const float* p = gA + (size_t)(m0 + ln) * K + kc * 32 + quad * 8;
            float4 u = *(const float4*)p;
            float4 v = *(const float4*)(p + 4);
            a[kc] = cvt8(u, v);
        }
    } else {
        #pragma unroll
        for (int kc = 0; kc < KC; ++kc)
            a[kc] = *(const bf16x8*)&ldsIn[ln * STRIN + kc * 32 + quad * 8];
    }

    f32x4 acc[NTH];
    #pragma unroll
    for (int nt = 0; nt < NTH; ++nt) acc[nt] = (f32x4){0.f, 0.f, 0.f, 0.f};

    #pragma unroll
    for (int kc = 0; kc < KC; ++kc)
        #pragma unroll
        for (int nt = 0; nt < NTH; ++nt) {
            bf16x8 b = *(const bf16x8*)(Wf + ((size_t)((w * NTH + nt) * KC + kc) * 64 + lane) * 8);
            acc[nt] = __builtin_amdgcn_mfma_f32_16x16x32_bf16(a[kc], b, acc[nt], 0, 0, 0);
        }

    #pragma unroll
    for (int nt = 0; nt < NTH; ++nt) {
        const int col = (w * NTH + nt) * 16 + ln;
        const float bv = bias[col];
        #pragma unroll
        for (int i = 0; i < 4; ++i) {
            const int row = quad * 4 + i;
            float v = acc[nt][i] + bv;
            if constexpr (RELU) v = fmaxf(v, 0.f);
            if constexpr (ADDK) v += bf2f(knowL[row * 72 + col]);
            if constexpr (OUTGLOBAL) gOut[(size_t)(m0 + row) * N + col] = v;
            else                     ldsOut[row * STROUT + col] = f2bf(v);
        }
    }
}

// ===== megakernel (R7 shape): 512 blocks x 256 threads, 16 rows/block =====
__global__ __launch_bounds__(256, 2) void mega(
    const float* __restrict__ x, const float* __restrict__ kg,
    const int* __restrict__ idx, const int* __restrict__ mask,
    const ushort* __restrict__ Wkgf, const float* __restrict__ bkg,
    const ushort* __restrict__ W1at, const float* __restrict__ b1a,
    const ushort* __restrict__ W1bt, const float* __restrict__ b1b,
    const ushort* __restrict__ W1ct, const float* __restrict__ b1c,
    const ushort* __restrict__ W1dt, const float* __restrict__ b1d,
    const ushort* __restrict__ W2t,  const float* __restrict__ b2,
    float* __restrict__ out)
{
    __shared__ ushort bufA[16 * 520];   // h2
    __shared__ ushort bufB[16 * 136];   // h1 / h3
    __shared__ ushort bufC[16 * 72];    // relu(h4)+know
    __shared__ ushort knowL[16 * 72];   // knowledge, local rows
    __shared__ int    sidxL[4][4][64];  // per-wave, per-sub compacted indices

    const int t = threadIdx.x;
    const int w = t >> 6, lane = t & 63, ln = lane & 15, quad = lane >> 4;
    const int m0 = blockIdx.x * 16;

    // ---------- knowledge: wave w handles batches m0 + w*4 .. +3 ----------
    // Wkg B-frags hoisted to registers (8 x 16B/lane, L2-hot)
    bf16x8 wb[4][2];
    #pragma unroll
    for (int nt = 0; nt < 4; ++nt)
        #pragma unroll
        for (int s = 0; s < 2; ++s)
            wb[nt][s] = *(const bf16x8*)(Wkgf + ((size_t)((nt * 2 + s) * 64 + lane)) * 8);

    // bkg hoisted
    float bkv[4];
    #pragma unroll
    for (int nt = 0; nt < 4; ++nt) bkv[nt] = bkg[nt * 16 + ln];

    // preload idx/mask, compact all 4 sub-batches upfront.
    // Default-fill with 0 so clamped gathers are always in-bounds;
    // rows >= cnt are zeroed by the masked sum, not by the load.
    int cnts[4];
    #pragma unroll
    for (int sub = 0; sub < 4; ++sub) {
        const int b = m0 + w * 4 + sub;
        int id = 0, mk = 0;
        if (lane < KCNT) {
            id = idx[(size_t)b * KCNT + lane];
            mk = mask[(size_t)b * KCNT + lane];
        }
        sidxL[w][sub][lane] = 0;
        unsigned long long bal = __ballot(mk != 0);
        cnts[sub] = __popcll(bal);
        if (mk) {
            int pos = __popcll(bal & ((1ull << lane) - 1ull));
            sidxL[w][sub][pos] = id;
        }
    }

    #pragma unroll 1
    for (int sub = 0; sub < 4; ++sub) {
        const int cnt    = cnts[sub];
        const int ntiles = (cnt + 15) >> 4;   // wave-uniform: 0..4 row-tiles
        float cs[4] = {0.f, 0.f, 0.f, 0.f};

        #pragma unroll
        for (int mt = 0; mt < 4; ++mt) {
            if (mt < ntiles) {                 // wave-uniform branch
                const int r = mt * 16 + ln;
                const float* p0 = kg + (size_t)sidxL[w][sub][r] * 64 + quad * 8;
                bf16x8 a0 = cvt8(*(const float4*)p0, *(const float4*)(p0 + 4));
                bf16x8 a1 = cvt8(*(const float4*)(p0 + 32), *(const float4*)(p0 + 36));

                f32x4 acc4[4];
                #pragma unroll
                for (int nt = 0; nt < 4; ++nt) acc4[nt] = (f32x4){0.f, 0.f, 0.f, 0.f};
                #pragma unroll
                for (int nt = 0; nt < 4; ++nt) {
                    acc4[nt] = __builtin_amdgcn_mfma_f32_16x16x32_bf16(a0, wb[nt][0], acc4[nt], 0, 0, 0);
                    acc4[nt] = __builtin_amdgcn_mfma_f32_16x16x32_bf16(a1, wb[nt][1], acc4[nt], 0, 0, 0);
                }
                // masked relu + column partial sum for this row-tile
                #pragma unroll
                for (int i = 0; i < 4; ++i) {
                    const int row = mt * 16 + quad * 4 + i;
                    const float mk = (row < cnt) ? 1.f : 0.f;
                    #pragma unroll
                    for (int nt = 0; nt < 4; ++nt)
                        cs[nt] += mk * fmaxf(acc4[nt][i] + bkv[nt], 0.f);
                }
            }
        }
        #pragma unroll
        for (int nt = 0; nt < 4; ++nt) {
            cs[nt] += __shfl_xor(cs[nt], 16, 64);
            cs[nt] += __shfl_xor(cs[nt], 32, 64);
        }
        if (quad == 0) {
            #pragma unroll
            for (int nt = 0; nt < 4; ++nt)
                knowL[(w * 4 + sub) * 72 + nt * 16 + ln] = f2bf(cs[nt]);
        }
    }

    // ---------- MLP chain (knowL visible to L4 via the L1..L3 barriers) ----------
    // L1: h1 = relu(x @ W1a + b1a)            512 -> 128 (A from global fp32)
    wave_layer<512, 128, 0, 136, true, true, false, false>(
        nullptr, x, bufB, W1at, b1a, nullptr, nullptr, m0, lane, w);
    __syncthreads();
    // L2: h2 = relu(h1 @ W1b + b1b)           128 -> 512
    wave_layer<128, 512, 136, 520, false, true, false, false>(
        bufB, nullptr, bufA, W1bt, b1b, nullptr, nullptr, m0, lane, w);
    __syncthreads();
    // L3: h3 = relu(h2 @ W1c + b1c)           512 -> 128
    wave_layer<512, 128, 520, 136, false, true, false, false>(
        bufA, nullptr, bufB, W1ct, b1c, nullptr, nullptr, m0, lane, w);
    __syncthreads();
    // L4: c = relu(h3 @ W1d + b1d) + knowledge   128 -> 64
    wave_layer<128, 64, 136, 72, false, true, true, false>(
        bufB, nullptr, bufC, W1dt, b1d, knowL, nullptr, m0, lane, w);
    __syncthreads();
    // L5: out = c @ W2 + b2 (fp32 to global)  64 -> 1024
    wave_layer<64, 1024, 72, 0, false, false, false, true>(
        bufC, nullptr, nullptr, W2t, b2, nullptr, out, m0, lane, w);
}

extern "C" void kernel_launch(void* const* d_in, const int* in_sizes, int n_in,
                              void* d_out, int out_size, void* d_ws, size_t ws_size,
                              hipStream_t stream)
{
    const float* x    = (const float*)d_in[0];
    const float* kg   = (const float*)d_in[1];
    const int*   idx  = (const int*)d_in[2];
    const int*   mask = (const int*)d_in[3];
    const float* Wkg  = (const float*)d_in[4];
    const float* bkg  = (const float*)d_in[5];
    const float* W1a  = (const float*)d_in[6];
    const float* b1a  = (const float*)d_in[7];
    const float* W1b  = (const float*)d_in[8];
    const float* b1b  = (const float*)d_in[9];
    const float* W1c  = (const float*)d_in[10];
    const float* b1c  = (const float*)d_in[11];
    const float* W1d  = (const float*)d_in[12];
    const float* b1d  = (const float*)d_in[13];
    const float* W2   = (const float*)d_in[14];
    const float* b2   = (const float*)d_in[15];
    float* out = (float*)d_out;

    // ws (ushorts): frag-major bf16 weights only (~540 KB)
    ushort* Wkgt = (ushort*)d_ws;                    // 64*64
    ushort* W1at = Wkgt + 64 * 64;                   // 512*128
    ushort* W1bt = W1at + 512 * 128;                 // 128*512
    ushort* W1ct = W1bt + 128 * 512;                 // 512*128
    ushort* W1dt = W1ct + 512 * 128;                 // 128*64
    ushort* W2t  = W1dt + 128 * 64;                  // 64*1024

    prep_weights<<<(274432 + 255) / 256, 256, 0, stream>>>(
        Wkg, Wkgt, W1a, W1at, W1b, W1bt, W1c, W1ct, W1d, W1dt, W2, W2t);

    mega<<<BB / 16, 256, 0, stream>>>(
        x, kg, idx, mask, Wkgt, bkg,
        W1at, b1a, W1bt, b1b, W1ct, b1c, W1dt, b1d, W2t, b2, out);
}

// Round 11
// 152.029 us; speedup vs baseline: 1.2223x; 1.0481x over previous
//
#include <hip/hip_runtime.h>
#include <hip/hip_bf16.h>

#define BB 8192
#define KCNT 50

typedef __attribute__((ext_vector_type(8))) short bf16x8;
typedef __attribute__((ext_vector_type(4))) float f32x4;

__device__ __forceinline__ ushort f2bf(float f) {
    union { float f; unsigned u; } v; v.f = f;
    unsigned r = v.u + 0x7FFFu + ((v.u >> 16) & 1u);
    return (ushort)(r >> 16);
}
__device__ __forceinline__ float bf2f(ushort h) {
    union { unsigned u; float f; } v; v.u = ((unsigned)h) << 16;
    return v.f;
}
// packed f32x8 -> bf16x8 via v_cvt_pk_bf16_f32 (RNE)
__device__ __forceinline__ bf16x8 cvt8(float4 u, float4 v) {
    union { bf16x8 r; __hip_bfloat162 h[4]; } o;
    o.h[0] = __float22bfloat162_rn(float2{u.x, u.y});
    o.h[1] = __float22bfloat162_rn(float2{u.z, u.w});
    o.h[2] = __float22bfloat162_rn(float2{v.x, v.y});
    o.h[3] = __float22bfloat162_rn(float2{v.z, v.w});
    return o.r;
}

// fragment-major index: frag f=(nt*KC+kc) holds a 16n x 32k block as
// 64 lanes x 16B, so reads at f*1024B + lane*16B are perfectly coalesced.
__device__ __forceinline__ int fidx(int K, int n, int k) {
    int nt = n >> 4, ln = n & 15, kc = k >> 5, quad = (k >> 3) & 3, j = k & 7;
    return (((nt * (K >> 5) + kc) * 4 + quad) * 16 + ln) * 8 + j;
}

// ---- prep: all 6 weights [K][N] fp32 -> fragment-major bf16 ----
__global__ __launch_bounds__(256) void prep_weights(
    const float* __restrict__ s0, ushort* __restrict__ d0,   // Wkg 64x64
    const float* __restrict__ s1, ushort* __restrict__ d1,   // W1a 512x128
    const float* __restrict__ s2, ushort* __restrict__ d2,   // W1b 128x512
    const float* __restrict__ s3, ushort* __restrict__ d3,   // W1c 512x128
    const float* __restrict__ s4, ushort* __restrict__ d4,   // W1d 128x64
    const float* __restrict__ s5, ushort* __restrict__ d5)   // W2 64x1024
{
    int gid = blockIdx.x * 256 + threadIdx.x;
    const float* s; ushort* d; int K, N, base;
    if      (gid < 4096)   { s = s0; d = d0; K = 64;  N = 64;   base = 0; }
    else if (gid < 69632)  { s = s1; d = d1; K = 512; N = 128;  base = 4096; }
    else if (gid < 135168) { s = s2; d = d2; K = 128; N = 512;  base = 69632; }
    else if (gid < 200704) { s = s3; d = d3; K = 512; N = 128;  base = 135168; }
    else if (gid < 208896) { s = s4; d = d4; K = 128; N = 64;   base = 200704; }
    else if (gid < 274432) { s = s5; d = d5; K = 64;  N = 1024; base = 208896; }
    else return;
    int e = gid - base;          // e = k*N + n  (coalesced read)
    int k = e / N, n = e % N;
    d[fidx(K, n, k)] = f2bf(s[e]);
}

// ---- per-wave layer (unchanged from R10) ----
template<int K, int N, int STRIN, int STROUT, bool AGLOBAL, bool RELU, bool ADDK, bool OUTGLOBAL>
__device__ __forceinline__ void wave_layer(
    const ushort* ldsIn, const float* __restrict__ gA, ushort* ldsOut,
    const ushort* __restrict__ Wf, const float* __restrict__ bias,
    const ushort* knowL, float* __restrict__ gOut,
    int m0, int lane, int w)
{
    constexpr int KC  = K / 32;
    constexpr int NTH = N / 64;       // n-tiles per wave (4 waves)
    const int ln = lane & 15, quad = lane >> 4;

    bf16x8 a[KC];
    if constexpr (AGLOBAL) {
        #pragma unroll
        for (int kc = 0; kc < KC; ++kc) {
            const float* p = gA + (size_t)(m0 + ln) * K + kc * 32 + quad * 8;
            float4 u = *(const float4*)p;
            float4 v = *(const float4*)(p + 4);
            a[kc] = cvt8(u, v);
        }
    } else {
        #pragma unroll
        for (int kc = 0; kc < KC; ++kc)
            a[kc] = *(const bf16x8*)&ldsIn[ln * STRIN + kc * 32 + quad * 8];
    }

    f32x4 acc[NTH];
    #pragma unroll
    for (int nt = 0; nt < NTH; ++nt) acc[nt] = (f32x4){0.f, 0.f, 0.f, 0.f};

    #pragma unroll
    for (int kc = 0; kc < KC; ++kc)
        #pragma unroll
        for (int nt = 0; nt < NTH; ++nt) {
            bf16x8 b = *(const bf16x8*)(Wf + ((size_t)((w * NTH + nt) * KC + kc) * 64 + lane) * 8);
            acc[nt] = __builtin_amdgcn_mfma_f32_16x16x32_bf16(a[kc], b, acc[nt], 0, 0, 0);
        }

    #pragma unroll
    for (int nt = 0; nt < NTH; ++nt) {
        const int col = (w * NTH + nt) * 16 + ln;
        const float bv = bias[col];
        #pragma unroll
        for (int i = 0; i < 4; ++i) {
            const int row = quad * 4 + i;
            float v = acc[nt][i] + bv;
            if constexpr (RELU) v = fmaxf(v, 0.f);
            if constexpr (ADDK) v += bf2f(knowL[row * 72 + col]);
            if constexpr (OUTGLOBAL)
                __builtin_nontemporal_store(v, &gOut[(size_t)(m0 + row) * N + col]);
            else
                ldsOut[row * STROUT + col] = f2bf(v);
        }
    }
}

// ===== megakernel: 512 blocks x 256 threads, 16 rows/block =====
__global__ __launch_bounds__(256, 2) void mega(
    const float* __restrict__ x, const float* __restrict__ kg,
    const int* __restrict__ idx, const int* __restrict__ mask,
    const ushort* __restrict__ Wkgf, const float* __restrict__ bkg,
    const ushort* __restrict__ W1at, const float* __restrict__ b1a,
    const ushort* __restrict__ W1bt, const float* __restrict__ b1b,
    const ushort* __restrict__ W1ct, const float* __restrict__ b1c,
    const ushort* __restrict__ W1dt, const float* __restrict__ b1d,
    const ushort* __restrict__ W2t,  const float* __restrict__ b2,
    float* __restrict__ out)
{
    __shared__ ushort bufA[16 * 520];   // h2
    __shared__ ushort bufB[16 * 136];   // h1 / h3
    __shared__ ushort bufC[16 * 72];    // relu(h4)+know
    __shared__ ushort knowL[16 * 72];   // knowledge, local rows
    __shared__ int    sidxL[4][4][64];  // per-wave, per-sub compacted indices

    const int t = threadIdx.x;
    const int w = t >> 6, lane = t & 63, ln = lane & 15, quad = lane >> 4;
    const int m0 = blockIdx.x * 16;

    // ---------- knowledge: wave w handles batches m0 + w*4 .. +3 ----------
    // Wkg B-frags hoisted to registers (8 x 16B/lane, L2-hot)
    bf16x8 wb[4][2];
    #pragma unroll
    for (int nt = 0; nt < 4; ++nt)
        #pragma unroll
        for (int s = 0; s < 2; ++s)
            wb[nt][s] = *(const bf16x8*)(Wkgf + ((size_t)((nt * 2 + s) * 64 + lane)) * 8);

    float bkv[4];
    #pragma unroll
    for (int nt = 0; nt < 4; ++nt) bkv[nt] = bkg[nt * 16 + ln];

    // compact all 4 sub-batches upfront; default index 0 so clamped gathers
    // are in-bounds (rows >= cnt zeroed by masked sum, and they all hit the
    // same kg row 0 -> L1-resident broadcast, nearly free).
    int cnts[4];
    #pragma unroll
    for (int sub = 0; sub < 4; ++sub) {
        const int b = m0 + w * 4 + sub;
        int id = 0, mk = 0;
        if (lane < KCNT) {
            id = idx[(size_t)b * KCNT + lane];
            mk = mask[(size_t)b * KCNT + lane];
        }
        sidxL[w][sub][lane] = 0;
        unsigned long long bal = __ballot(mk != 0);
        cnts[sub] = __popcll(bal);
        if (mk) {
            int pos = __popcll(bal & ((1ull << lane) - 1ull));
            sidxL[w][sub][pos] = id;
        }
    }

    // ---- phase 1: issue ALL gather loads (tiles 0-1, all subs) ----
    // 32 independent float4 loads in flight -> one latency round-trip
    // instead of four.
    float4 graw[4][2][4];
    #pragma unroll
    for (int sub = 0; sub < 4; ++sub)
        #pragma unroll
        for (int mt = 0; mt < 2; ++mt) {
            const int r = mt * 16 + ln;
            const float* p0 = kg + (size_t)sidxL[w][sub][r] * 64 + quad * 8;
            graw[sub][mt][0] = *(const float4*)p0;
            graw[sub][mt][1] = *(const float4*)(p0 + 4);
            graw[sub][mt][2] = *(const float4*)(p0 + 32);
            graw[sub][mt][3] = *(const float4*)(p0 + 36);
        }

    // ---- phase 2: convert (in issue order; frees raw regs progressively) ----
    bf16x8 ga[4][2][2];
    #pragma unroll
    for (int sub = 0; sub < 4; ++sub)
        #pragma unroll
        for (int mt = 0; mt < 2; ++mt) {
            ga[sub][mt][0] = cvt8(graw[sub][mt][0], graw[sub][mt][1]);
            ga[sub][mt][1] = cvt8(graw[sub][mt][2], graw[sub][mt][3]);
        }

    // ---- phase 3: MFMA + masked column-sum per sub ----
    #pragma unroll
    for (int sub = 0; sub < 4; ++sub) {
        const int cnt = cnts[sub];
        float cs[4] = {0.f, 0.f, 0.f, 0.f};

        #pragma unroll
        for (int mt = 0; mt < 2; ++mt) {
            f32x4 acc4[4];
            #pragma unroll
            for (int nt = 0; nt < 4; ++nt) acc4[nt] = (f32x4){0.f, 0.f, 0.f, 0.f};
            #pragma unroll
            for (int nt = 0; nt < 4; ++nt) {
                acc4[nt] = __builtin_amdgcn_mfma_f32_16x16x32_bf16(ga[sub][mt][0], wb[nt][0], acc4[nt], 0, 0, 0);
                acc4[nt] = __builtin_amdgcn_mfma_f32_16x16x32_bf16(ga[sub][mt][1], wb[nt][1], acc4[nt], 0, 0, 0);
            }
            #pragma unroll
            for (int i = 0; i < 4; ++i) {
                const int row = mt * 16 + quad * 4 + i;
                const float mk = (row < cnt) ? 1.f : 0.f;
                #pragma unroll
                for (int nt = 0; nt < 4; ++nt)
                    cs[nt] += mk * fmaxf(acc4[nt][i] + bkv[nt], 0.f);
            }
        }
        // rare tail: cnt > 32 needs tiles 2-3 (wave-uniform, ~3% of subs)
        if (cnt > 32) {
            #pragma unroll
            for (int mt = 2; mt < 4; ++mt) {
                const int r = mt * 16 + ln;
                const float* p0 = kg + (size_t)sidxL[w][sub][r] * 64 + quad * 8;
                bf16x8 a0 = cvt8(*(const float4*)p0, *(const float4*)(p0 + 4));
                bf16x8 a1 = cvt8(*(const float4*)(p0 + 32), *(const float4*)(p0 + 36));
                f32x4 acc4[4];
                #pragma unroll
                for (int nt = 0; nt < 4; ++nt) acc4[nt] = (f32x4){0.f, 0.f, 0.f, 0.f};
                #pragma unroll
                for (int nt = 0; nt < 4; ++nt) {
                    acc4[nt] = __builtin_amdgcn_mfma_f32_16x16x32_bf16(a0, wb[nt][0], acc4[nt], 0, 0, 0);
                    acc4[nt] = __builtin_amdgcn_mfma_f32_16x16x32_bf16(a1, wb[nt][1], acc4[nt], 0, 0, 0);
                }
                #pragma unroll
                for (int i = 0; i < 4; ++i) {
                    const int row = mt * 16 + quad * 4 + i;
                    const float mk = (row < cnt) ? 1.f : 0.f;
                    #pragma unroll
                    for (int nt = 0; nt < 4; ++nt)
                        cs[nt] += mk * fmaxf(acc4[nt][i] + bkv[nt], 0.f);
                }
            }
        }

        #pragma unroll
        for (int nt = 0; nt < 4; ++nt) {
            cs[nt] += __shfl_xor(cs[nt], 16, 64);
            cs[nt] += __shfl_xor(cs[nt], 32, 64);
        }
        if (quad == 0) {
            #pragma unroll
            for (int nt = 0; nt < 4; ++nt)
                knowL[(w * 4 + sub) * 72 + nt * 16 + ln] = f2bf(cs[nt]);
        }
    }

    // ---------- MLP chain ----------
    // L1: h1 = relu(x @ W1a + b1a)            512 -> 128 (A from global fp32)
    wave_layer<512, 128, 0, 136, true, true, false, false>(
        nullptr, x, bufB, W1at, b1a, nullptr, nullptr, m0, lane, w);
    __syncthreads();
    // L2: h2 = relu(h1 @ W1b + b1b)           128 -> 512
    wave_layer<128, 512, 136, 520, false, true, false, false>(
        bufB, nullptr, bufA, W1bt, b1b, nullptr, nullptr, m0, lane, w);
    __syncthreads();
    // L3: h3 = relu(h2 @ W1c + b1c)           512 -> 128
    wave_layer<512, 128, 520, 136, false, true, false, false>(
        bufA, nullptr, bufB, W1ct, b1c, nullptr, nullptr, m0, lane, w);
    __syncthreads();
    // L4: c = relu(h3 @ W1d + b1d) + knowledge   128 -> 64
    wave_layer<128, 64, 136, 72, false, true, true, false>(
        bufB, nullptr, bufC, W1dt, b1d, knowL, nullptr, m0, lane, w);
    __syncthreads();
    // L5: out = c @ W2 + b2 (fp32, nontemporal)  64 -> 1024
    wave_layer<64, 1024, 72, 0, false, false, false, true>(
        bufC, nullptr, nullptr, W2t, b2, nullptr, out, m0, lane, w);
}

extern "C" void kernel_launch(void* const* d_in, const int* in_sizes, int n_in,
                              void* d_out, int out_size, void* d_ws, size_t ws_size,
                              hipStream_t stream)
{
    const float* x    = (const float*)d_in[0];
    const float* kg   = (const float*)d_in[1];
    const int*   idx  = (const int*)d_in[2];
    const int*   mask = (const int*)d_in[3];
    const float* Wkg  = (const float*)d_in[4];
    const float* bkg  = (const float*)d_in[5];
    const float* W1a  = (const float*)d_in[6];
    const float* b1a  = (const float*)d_in[7];
    const float* W1b  = (const float*)d_in[8];
    const float* b1b  = (const float*)d_in[9];
    const float* W1c  = (const float*)d_in[10];
    const float* b1c  = (const float*)d_in[11];
    const float* W1d  = (const float*)d_in[12];
    const float* b1d  = (const float*)d_in[13];
    const float* W2   = (const float*)d_in[14];
    const float* b2   = (const float*)d_in[15];
    float* out = (float*)d_out;

    // ws (ushorts): frag-major bf16 weights only (~540 KB)
    ushort* Wkgt = (ushort*)d_ws;                    // 64*64
    ushort* W1at = Wkgt + 64 * 64;                   // 512*128
    ushort* W1bt = W1at + 512 * 128;                 // 128*512
    ushort* W1ct = W1bt + 128 * 512;                 // 512*128
    ushort* W1dt = W1ct + 512 * 128;                 // 128*64
    ushort* W2t  = W1dt + 128 * 64;                  // 64*1024

    prep_weights<<<(274432 + 255) / 256, 256, 0, stream>>>(
        Wkg, Wkgt, W1a, W1at, W1b, W1bt, W1c, W1ct, W1d, W1dt, W2, W2t);

    mega<<<BB / 16, 256, 0, stream>>>(
        x, kg, idx, mask, Wkgt, bkg,
        W1at, b1a, W1bt, b1b, W1ct, b1c, W1dt, b1d, W2t, b2, out);
}